// Round 6
// baseline (718.475 us; speedup 1.0000x reference)
//
#include <hip/hip_runtime.h>
#include <stdint.h>

// ---------------------------------------------------------------------------
// DkNN round 6: row-granularity candidates emitted from the GEMM epilogue.
//  Pass 1 (mfma_cand): single-product Ah*Bh bf16 MFMA GEMM (K=256). Epilogue:
//    per-(q, n-tile) min (LDS skey), then a second register pass emits every
//    row with sc <= tilemin + W into a per-query candidate list (~1.5/tile).
//    Error bound: bf16 (7 mantissa bits) rel err <= 2^-8 per operand ->
//    |d2_approx - d2_exact| <= 2*|a||b|*2^-7 ~= 0.019 < W/2 (W = 0.04), so
//    the true argmin row always qualifies within its own tile.
//  Pass 2 (refine_classify): one wave per query: min over list -> M; rows
//    with score <= M + W (~1.3/query) rescored exactly in fp32 (1 KB each);
//    then classify (bincount + conformal p-values) in the same wave.
// ---------------------------------------------------------------------------

typedef __attribute__((ext_vector_type(8))) short short8;   // 8 bf16 = 4 VGPR
typedef __attribute__((ext_vector_type(4))) float float4v;  // MFMA C/D

#define CAND_CAP 4096
#define WND 0.04f

static __device__ __forceinline__ unsigned short bf16_rn(float f) {
    unsigned int u = __float_as_uint(f);
    unsigned int r = (u + 0x7FFFu + ((u >> 16) & 1u)) >> 16;
    return (unsigned short)r;
}

static __device__ __forceinline__ void gload_lds16(const void* g, void* l) {
    __builtin_amdgcn_global_load_lds(
        (const __attribute__((address_space(1))) unsigned int*)g,
        (__attribute__((address_space(3))) unsigned int*)l, 16, 0, 0);
}

// Fused prep: blocks [0, Np/4) convert train rows (hi-bf16 + norm); blocks
// [Np/4, Np/4+Mp) prep one query row (normalize, center, hi-bf16, fp32 copy,
// q2, gkey/cnt init).
__global__ void prep_all(const float* __restrict__ X, const float* __restrict__ x,
                         const float* __restrict__ center,
                         unsigned short* __restrict__ Bh, float* __restrict__ xn2,
                         unsigned short* __restrict__ Ah, float* __restrict__ xqf,
                         float* __restrict__ q2, unsigned long long* __restrict__ gkey,
                         int* __restrict__ cnt,
                         int nb_train, int Np, int B, int Mp) {
    const int tid = threadIdx.x;
    const int tb = Np >> 2;
    if (blockIdx.x < (unsigned)tb) {
        int row = blockIdx.x * 4 + (tid >> 6);
        int lane = tid & 63;
        if (row >= nb_train) {
            *(ushort4*)(Bh + (size_t)row * 256 + lane * 4) = make_ushort4(0, 0, 0, 0);
            if (lane == 0) xn2[row] = 3.0e38f;
            return;
        }
        float4 v = ((const float4*)(X + (size_t)row * 256))[lane];
        ushort4 h;
        h.x = bf16_rn(v.x); h.y = bf16_rn(v.y);
        h.z = bf16_rn(v.z); h.w = bf16_rn(v.w);
        *(ushort4*)(Bh + (size_t)row * 256 + lane * 4) = h;
        float ss = v.x * v.x + v.y * v.y + v.z * v.z + v.w * v.w;
        #pragma unroll
        for (int s = 1; s < 64; s <<= 1) ss += __shfl_xor(ss, s);
        if (lane == 0) xn2[row] = ss;
        return;
    }
    int row = blockIdx.x - tb;
    if (row >= Mp) return;
    if (tid == 0) { gkey[row] = ~0ULL; cnt[row] = 0; }
    if (row >= B) {
        Ah[(size_t)row * 256 + tid] = 0;
        if (tid == 0) q2[row] = 0.0f;
        return;
    }
    float v = x[(size_t)row * 256 + tid];
    float ss = v * v;
    #pragma unroll
    for (int s = 1; s < 64; s <<= 1) ss += __shfl_xor(ss, s);
    __shared__ float partial[4];
    __shared__ float partial2[4];
    if ((tid & 63) == 0) partial[tid >> 6] = ss;
    __syncthreads();
    float tot = partial[0] + partial[1] + partial[2] + partial[3];
    float inv = 1.0f / sqrtf(tot);
    float val = v * inv - center[tid];
    Ah[(size_t)row * 256 + tid] = bf16_rn(val);
    xqf[(size_t)row * 256 + tid] = val;
    float ss2 = val * val;
    #pragma unroll
    for (int s = 1; s < 64; s <<= 1) ss2 += __shfl_xor(ss2, s);
    if ((tid & 63) == 0) partial2[tid >> 6] = ss2;
    __syncthreads();
    if (tid == 0) q2[row] = partial2[0] + partial2[1] + partial2[2] + partial2[3];
}

// 128x128 tile, 4 waves x 64x64 quadrants, K=256 in 4 steps of BK=64.
// XCD-swizzled 1D grid. Epilogue: tile-min -> gkey atomicMin; then emission
// of all rows with sc <= tilemin + WND into the per-query candidate list.
__global__ __launch_bounds__(256, 4) void mfma_cand(
    const unsigned short* __restrict__ Ah,  // Mp x 256 bf16
    const unsigned short* __restrict__ Bh,  // Np x 256 bf16
    const float* __restrict__ q2, const float* __restrict__ xn2,
    unsigned long long* __restrict__ gkey,
    int* __restrict__ cnt, unsigned long long* __restrict__ entries,
    int nb_train, int B, int ntiles, int nper, int mtiles)
{
    __shared__ unsigned short As[128 * 64];   // [row][chunk ^ (row&7)] 16B chunks
    __shared__ unsigned short Bs[128 * 64];
    __shared__ unsigned long long skey[128];

    const int bid = blockIdx.x;
    const int xcd = bid & 7;
    const int s_  = bid >> 3;
    const int n_t = xcd * nper + (s_ / mtiles);
    const int m_t = s_ - (s_ / mtiles) * mtiles;
    if (n_t >= ntiles) return;
    const int mtile = m_t * 128;
    const int ntile = n_t * 128;

    const int tid  = threadIdx.x;
    const int wave = tid >> 6;
    const int lane = tid & 63;

    if (tid < 128) skey[tid] = ~0ULL;

    // staging role: waves 0,1 stage A rows [0:64),[64:128); waves 2,3 for B
    const int isB   = wave >> 1;
    const int Rwave = (wave & 1) * 64;
    const int lrow8  = lane >> 3;
    const int lchunk = lane & 7;
    const unsigned short* sbase = isB
        ? (Bh + (size_t)(ntile + Rwave + lrow8) * 256 + (size_t)((lchunk ^ lrow8) * 8))
        : (Ah + (size_t)(mtile + Rwave + lrow8) * 256 + (size_t)((lchunk ^ lrow8) * 8));
    unsigned short* lwave = (isB ? Bs : As) + Rwave * 64;

    // compute role: quadrant
    const int mq = (wave >> 1) * 64;
    const int nq = (wave & 1) * 64;
    const int lrow = lane & 15;
    const int kseg = lane >> 4;
    const int sw = lrow & 7;

    float4v acc[4][4];
    #pragma unroll
    for (int i = 0; i < 4; ++i)
        #pragma unroll
        for (int j = 0; j < 4; ++j)
            acc[i][j] = (float4v){0.f, 0.f, 0.f, 0.f};

    for (int s = 0; s < 4; ++s) {
        const unsigned short* g = sbase + s * 64;
        __syncthreads();
        #pragma unroll
        for (int q = 0; q < 8; ++q)
            gload_lds16(g + q * 2048, lwave + q * 512);
        __syncthreads();
        #pragma unroll
        for (int t = 0; t < 2; ++t) {
            const int wch = ((t * 4 + kseg) ^ sw) * 8;
            short8 a[4], b[4];
            #pragma unroll
            for (int i = 0; i < 4; ++i)
                a[i] = *(const short8*)&As[(mq + i * 16 + lrow) * 64 + wch];
            #pragma unroll
            for (int j = 0; j < 4; ++j)
                b[j] = *(const short8*)&Bs[(nq + j * 16 + lrow) * 64 + wch];
            #pragma unroll
            for (int i = 0; i < 4; ++i)
                #pragma unroll
                for (int j = 0; j < 4; ++j)
                    acc[i][j] = __builtin_amdgcn_mfma_f32_16x16x32_bf16(
                        a[i], b[j], acc[i][j], 0, 0, 0);
        }
    }

    float xnv[4];
    #pragma unroll
    for (int j = 0; j < 4; ++j)
        xnv[j] = xn2[ntile + nq + j * 16 + lrow];   // pads hold 3e38

    // ---- pass 1: per-(q,tile) min -> skey; block result -> gkey ----
    #pragma unroll
    for (int i = 0; i < 4; ++i) {
        #pragma unroll
        for (int r = 0; r < 4; ++r) {
            const int lm = mq + i * 16 + kseg * 4 + r;
            const int mi = mtile + lm;
            unsigned long long best = ~0ULL;
            if (mi < B) {
                float q2v = q2[mi];
                #pragma unroll
                for (int j = 0; j < 4; ++j) {
                    int t_ = ntile + nq + j * 16 + lrow;
                    float sc = fmaxf(q2v - 2.0f * acc[i][j][r] + xnv[j], 0.0f);
                    unsigned long long key =
                        ((unsigned long long)__float_as_uint(sc) << 32) | (unsigned int)t_;
                    best = (key < best) ? key : best;
                }
            }
            #pragma unroll
            for (int sft = 1; sft < 16; sft <<= 1) {
                unsigned long long o = __shfl_xor(best, sft);
                best = (o < best) ? o : best;
            }
            if (lrow == 0 && mi < B) atomicMin(&skey[lm], best);
        }
    }
    __syncthreads();
    if (tid < 128) {
        int mi = mtile + tid;
        if (mi < B) atomicMin(gkey + mi, skey[tid]);
    }
    __syncthreads();

    // ---- pass 2: emit rows with sc <= tilemin + WND into candidate list ----
    #pragma unroll
    for (int i = 0; i < 4; ++i) {
        #pragma unroll
        for (int r = 0; r < 4; ++r) {
            const int lm = mq + i * 16 + kseg * 4 + r;
            const int mi = mtile + lm;
            if (mi < B) {
                const float thr =
                    __uint_as_float((unsigned)(skey[lm] >> 32)) + WND;
                const float q2v = q2[mi];
                #pragma unroll
                for (int j = 0; j < 4; ++j) {
                    int t_ = ntile + nq + j * 16 + lrow;
                    float sc = fmaxf(q2v - 2.0f * acc[i][j][r] + xnv[j], 0.0f);
                    if (sc <= thr) {
                        int pos = atomicAdd(&cnt[mi], 1);
                        if (pos < CAND_CAP) {
                            unsigned long long key =
                                ((unsigned long long)__float_as_uint(sc) << 32) |
                                (unsigned int)t_;
                            entries[(size_t)mi * CAND_CAP + pos] = key;
                        }
                    }
                }
            }
        }
    }
}

// One wave per query: list-min -> M; exact fp32 rescore of rows <= M + WND
// (plus the gkey row as a safety seed); then bincount + conformal p-values.
__global__ __launch_bounds__(256) void refine_classify(
    const unsigned long long* __restrict__ entries, const int* __restrict__ cnt,
    const unsigned long long* __restrict__ gkey,
    const float* __restrict__ xqf, const float* __restrict__ q2,
    const float* __restrict__ X, const float* __restrict__ xn2,
    const int* __restrict__ labels, const int* __restrict__ nbr,
    const int* __restrict__ cali, float* __restrict__ out,
    int knm1, int nb_cali, int nb_train, int B)
{
    __shared__ int ccnt[4];
    __shared__ unsigned long long cbuf[4][64];
    const int w = threadIdx.x >> 6;
    const int lane = threadIdx.x & 63;
    const int q = blockIdx.x * 4 + w;
    if (q >= B) return;   // B is a multiple of 4 in practice; guard anyway
    if (lane == 0) ccnt[w] = 0;
    __syncthreads();

    int n = cnt[q]; if (n > CAND_CAP) n = CAND_CAP;
    const unsigned long long* E = entries + (size_t)q * CAND_CAP;
    unsigned long long M = gkey[q];
    for (int i = lane; i < n; i += 64) {
        unsigned long long e = E[i];
        M = (e < M) ? e : M;
    }
    #pragma unroll
    for (int s = 1; s < 64; s <<= 1) {
        unsigned long long o = __shfl_xor(M, s);
        M = (o < M) ? o : M;
    }
    const float thr = __uint_as_float((unsigned)(M >> 32)) + WND;
    for (int i = lane; i < n; i += 64) {
        unsigned long long e = E[i];
        if (__uint_as_float((unsigned)(e >> 32)) <= thr) {
            int p = atomicAdd(&ccnt[w], 1);
            if (p < 64) cbuf[w][p] = e;
        }
    }
    __syncthreads();
    int nc = ccnt[w]; if (nc > 64) nc = 64;

    // exact fp32 rescore: gkey row + all candidates
    const float4 qa = ((const float4*)(xqf + (size_t)q * 256))[lane];
    const float q2v = q2[q];
    const int gi = (int)(gkey[q] & 0xFFFFFFFFULL);
    unsigned long long best = ~0ULL;
    for (int k = -1; k < nc; ++k) {
        int t = (k < 0) ? gi : (int)(cbuf[w][k] & 0xFFFFFFFFULL);
        float4 b = ((const float4*)(X + (size_t)t * 256))[lane];
        float dot = qa.x * b.x + qa.y * b.y + qa.z * b.z + qa.w * b.w;
        #pragma unroll
        for (int s = 1; s < 64; s <<= 1) dot += __shfl_xor(dot, s);
        float sc = fmaxf(q2v - 2.0f * dot + xn2[t], 0.0f);
        unsigned long long key =
            ((unsigned long long)__float_as_uint(sc) << 32) | (unsigned)t;
        best = (key < best) ? key : best;
    }
    const int closest = (int)(best & 0xFFFFFFFFULL);

    // ---- classify ----
    const int K = knm1 + 1;   // 75
    int lbl0 = -1, lbl1 = -1;
    if (lane < K) {
        int idx = (lane == 0) ? closest : nbr[(size_t)closest * knm1 + (lane - 1)];
        lbl0 = labels[idx];
    }
    int j2 = lane + 64;
    if (j2 < K) {
        int idx = nbr[(size_t)closest * knm1 + (j2 - 1)];
        lbl1 = labels[idx];
    }
    int bestc = 0, bestp = -1;
    #pragma unroll
    for (int c = 0; c < 10; ++c) {
        int cn = __popcll(__ballot(lbl0 == c)) + __popcll(__ballot(lbl1 == c));
        int v = K - cn;
        int lo = 0, hi = nb_cali;
        while (lo < hi) {                 // bisect_left
            int mid = (lo + hi) >> 1;
            if (cali[mid] < v) lo = mid + 1; else hi = mid;
        }
        int p = nb_cali - lo;
        if (p > bestp) { bestp = p; bestc = c; }   // strict > == first-occurrence
    }
    float pv = (float)bestp / (float)nb_cali;
    if (lane < 10)
        out[(size_t)q * 10 + lane] = (lane == bestc) ? pv : 0.0f;
}

extern "C" void kernel_launch(void* const* d_in, const int* in_sizes, int n_in,
                              void* d_out, int out_size, void* d_ws, size_t ws_size,
                              hipStream_t stream) {
    const float* x      = (const float*)d_in[0];
    const float* X      = (const float*)d_in[1];
    const float* center = (const float*)d_in[2];
    const int* labels   = (const int*)d_in[3];
    const int* nbr      = (const int*)d_in[4];
    const int* cali     = (const int*)d_in[5];
    float* out = (float*)d_out;

    const int d        = in_sizes[2];              // 256
    const int B        = in_sizes[0] / d;          // 1024
    const int nb_train = in_sizes[3];              // 100000
    const int knm1     = in_sizes[4] / nb_train;   // 74
    const int nb_cali  = in_sizes[5];              // 1000

    const int Mp = (B + 127) & ~127;               // 1024
    const int Np = (nb_train + 127) & ~127;        // 100096
    const int ntiles = Np / 128;                   // 782
    const int mtiles = Mp / 128;                   // 8
    const int nper   = (ntiles + 7) / 8;           // 98

    char* ws = (char*)d_ws;
    size_t off = 0;
    unsigned long long* gkey    = (unsigned long long*)(ws + off); off += (size_t)Mp * 8;
    unsigned long long* entries = (unsigned long long*)(ws + off); off += (size_t)Mp * CAND_CAP * 8;
    int*   cnt  = (int*)(ws + off);   off += (size_t)Mp * 4;
    float* q2   = (float*)(ws + off); off += (size_t)Mp * 4;
    float* xqf  = (float*)(ws + off); off += (size_t)Mp * 256 * 4;
    float* xn2  = (float*)(ws + off); off += (size_t)Np * 4;
    unsigned short* Ah = (unsigned short*)(ws + off); off += (size_t)Mp * 256 * 2;
    unsigned short* Bh = (unsigned short*)(ws + off); off += (size_t)Np * 256 * 2;

    prep_all<<<Np / 4 + Mp, 256, 0, stream>>>(X, x, center, Bh, xn2,
                                              Ah, xqf, q2, gkey, cnt,
                                              nb_train, Np, B, Mp);
    mfma_cand<<<8 * nper * mtiles, 256, 0, stream>>>(
        Ah, Bh, q2, xn2, gkey, cnt, entries, nb_train, B, ntiles, nper, mtiles);
    refine_classify<<<(B + 3) / 4, 256, 0, stream>>>(
        entries, cnt, gkey, xqf, q2, X, xn2, labels, nbr, cali, out,
        knm1, nb_cali, nb_train, B);
}

// Round 7
// 418.332 us; speedup vs baseline: 1.7175x; 1.7175x over previous
//
#include <hip/hip_runtime.h>
#include <stdint.h>

// ---------------------------------------------------------------------------
// DkNN round 7: zero-global-atomic prefilter + exact refine.
//  K1 prep_all:  train rows -> bf16 Bh + xn2 ; queries -> normalized/centered
//                fp32 xqf + bf16 Ah + q2.
//  K2 mfma_min:  single-product Ah*Bh bf16 MFMA GEMM (K=256), 128x128 tiles,
//                XCD-swizzled. Epilogue: per-(q,tile) packed min key stored to
//                tilekey[tile][q] (contiguous 1KB store/block, NO atomics).
//  K3 finish:    one block/query: min over 782 tile keys -> M (approx).
//                Tiles with tilemin <= M+0.04 (argmin tile guaranteed: bf16
//                error |d2~ - d2| <= 2|a||b|2^-8 < 0.019, 2*0.019 < 0.04)
//                -> rescore 128 rows from bf16 Bh in fp32 VALU (same bound),
//                rows <= M+0.04 -> exact fp32 rescore from X -> true argmin
//                -> classify (bincount + conformal p-values) fused.
// ---------------------------------------------------------------------------

typedef __attribute__((ext_vector_type(8))) short short8;   // 8 bf16 = 4 VGPR
typedef __attribute__((ext_vector_type(8))) unsigned short ushort8;
typedef __attribute__((ext_vector_type(4))) float float4v;  // MFMA C/D

#define WND 0.04f
#define TCAP 32
#define CCAP 32

static __device__ __forceinline__ unsigned short bf16_rn(float f) {
    unsigned int u = __float_as_uint(f);
    unsigned int r = (u + 0x7FFFu + ((u >> 16) & 1u)) >> 16;
    return (unsigned short)r;
}

static __device__ __forceinline__ void gload_lds16(const void* g, void* l) {
    __builtin_amdgcn_global_load_lds(
        (const __attribute__((address_space(1))) unsigned int*)g,
        (__attribute__((address_space(3))) unsigned int*)l, 16, 0, 0);
}

// Fused prep: blocks [0, Np/4) convert train rows; blocks [Np/4, Np/4+Mp)
// prep one query row each.
__global__ void prep_all(const float* __restrict__ X, const float* __restrict__ x,
                         const float* __restrict__ center,
                         unsigned short* __restrict__ Bh, float* __restrict__ xn2,
                         unsigned short* __restrict__ Ah, float* __restrict__ xqf,
                         float* __restrict__ q2,
                         int nb_train, int Np, int B, int Mp) {
    const int tid = threadIdx.x;
    const int tb = Np >> 2;
    if (blockIdx.x < (unsigned)tb) {
        int row = blockIdx.x * 4 + (tid >> 6);
        int lane = tid & 63;
        if (row >= nb_train) {
            *(ushort4*)(Bh + (size_t)row * 256 + lane * 4) = make_ushort4(0, 0, 0, 0);
            if (lane == 0) xn2[row] = 3.0e38f;
            return;
        }
        float4 v = ((const float4*)(X + (size_t)row * 256))[lane];
        ushort4 h;
        h.x = bf16_rn(v.x); h.y = bf16_rn(v.y);
        h.z = bf16_rn(v.z); h.w = bf16_rn(v.w);
        *(ushort4*)(Bh + (size_t)row * 256 + lane * 4) = h;
        float ss = v.x * v.x + v.y * v.y + v.z * v.z + v.w * v.w;
        #pragma unroll
        for (int s = 1; s < 64; s <<= 1) ss += __shfl_xor(ss, s);
        if (lane == 0) xn2[row] = ss;
        return;
    }
    int row = blockIdx.x - tb;
    if (row >= Mp) return;
    if (row >= B) {
        Ah[(size_t)row * 256 + tid] = 0;
        if (tid == 0) q2[row] = 0.0f;
        return;
    }
    float v = x[(size_t)row * 256 + tid];
    float ss = v * v;
    #pragma unroll
    for (int s = 1; s < 64; s <<= 1) ss += __shfl_xor(ss, s);
    __shared__ float partial[4];
    __shared__ float partial2[4];
    if ((tid & 63) == 0) partial[tid >> 6] = ss;
    __syncthreads();
    float tot = partial[0] + partial[1] + partial[2] + partial[3];
    float inv = 1.0f / sqrtf(tot);
    float val = v * inv - center[tid];
    Ah[(size_t)row * 256 + tid] = bf16_rn(val);
    xqf[(size_t)row * 256 + tid] = val;
    float ss2 = val * val;
    #pragma unroll
    for (int s = 1; s < 64; s <<= 1) ss2 += __shfl_xor(ss2, s);
    if ((tid & 63) == 0) partial2[tid >> 6] = ss2;
    __syncthreads();
    if (tid == 0) q2[row] = partial2[0] + partial2[1] + partial2[2] + partial2[3];
}

// 128x128 tile, 4 waves x 64x64 quadrants, K=256 in 4 steps of BK=64.
// XCD-swizzled 1D grid. Epilogue: per-(q,tile) packed min -> tilekey[n_t][q]
// (contiguous store, no global atomics).
__global__ __launch_bounds__(256, 4) void mfma_min(
    const unsigned short* __restrict__ Ah,  // Mp x 256 bf16
    const unsigned short* __restrict__ Bh,  // Np x 256 bf16
    const float* __restrict__ q2, const float* __restrict__ xn2,
    unsigned long long* __restrict__ tilekey,   // [ntiles][Mp]
    int nb_train, int B, int Mp, int ntiles, int nper, int mtiles)
{
    __shared__ unsigned short As[128 * 64];   // [row][chunk ^ (row&7)] 16B chunks
    __shared__ unsigned short Bs[128 * 64];
    __shared__ unsigned long long skey[128];

    const int bid = blockIdx.x;
    const int xcd = bid & 7;
    const int s_  = bid >> 3;
    const int n_t = xcd * nper + (s_ / mtiles);
    const int m_t = s_ - (s_ / mtiles) * mtiles;
    if (n_t >= ntiles) return;
    const int mtile = m_t * 128;
    const int ntile = n_t * 128;

    const int tid  = threadIdx.x;
    const int wave = tid >> 6;
    const int lane = tid & 63;

    if (tid < 128) skey[tid] = ~0ULL;

    // staging role: waves 0,1 stage A rows [0:64),[64:128); waves 2,3 for B
    const int isB   = wave >> 1;
    const int Rwave = (wave & 1) * 64;
    const int lrow8  = lane >> 3;
    const int lchunk = lane & 7;
    const unsigned short* sbase = isB
        ? (Bh + (size_t)(ntile + Rwave + lrow8) * 256 + (size_t)((lchunk ^ lrow8) * 8))
        : (Ah + (size_t)(mtile + Rwave + lrow8) * 256 + (size_t)((lchunk ^ lrow8) * 8));
    unsigned short* lwave = (isB ? Bs : As) + Rwave * 64;

    // compute role: quadrant
    const int mq = (wave >> 1) * 64;
    const int nq = (wave & 1) * 64;
    const int lrow = lane & 15;
    const int kseg = lane >> 4;
    const int sw = lrow & 7;

    float4v acc[4][4];
    #pragma unroll
    for (int i = 0; i < 4; ++i)
        #pragma unroll
        for (int j = 0; j < 4; ++j)
            acc[i][j] = (float4v){0.f, 0.f, 0.f, 0.f};

    for (int s = 0; s < 4; ++s) {
        const unsigned short* g = sbase + s * 64;
        __syncthreads();
        #pragma unroll
        for (int q = 0; q < 8; ++q)
            gload_lds16(g + q * 2048, lwave + q * 512);
        __syncthreads();
        #pragma unroll
        for (int t = 0; t < 2; ++t) {
            const int wch = ((t * 4 + kseg) ^ sw) * 8;
            short8 a[4], b[4];
            #pragma unroll
            for (int i = 0; i < 4; ++i)
                a[i] = *(const short8*)&As[(mq + i * 16 + lrow) * 64 + wch];
            #pragma unroll
            for (int j = 0; j < 4; ++j)
                b[j] = *(const short8*)&Bs[(nq + j * 16 + lrow) * 64 + wch];
            #pragma unroll
            for (int i = 0; i < 4; ++i)
                #pragma unroll
                for (int j = 0; j < 4; ++j)
                    acc[i][j] = __builtin_amdgcn_mfma_f32_16x16x32_bf16(
                        a[i], b[j], acc[i][j], 0, 0, 0);
        }
    }

    float xnv[4];
    #pragma unroll
    for (int j = 0; j < 4; ++j)
        xnv[j] = xn2[ntile + nq + j * 16 + lrow];   // pads hold 3e38

    #pragma unroll
    for (int i = 0; i < 4; ++i) {
        #pragma unroll
        for (int r = 0; r < 4; ++r) {
            const int lm = mq + i * 16 + kseg * 4 + r;
            const int mi = mtile + lm;
            unsigned long long best = ~0ULL;
            if (mi < B) {
                float q2v = q2[mi];
                #pragma unroll
                for (int j = 0; j < 4; ++j) {
                    int t_ = ntile + nq + j * 16 + lrow;
                    float sc = fmaxf(q2v - 2.0f * acc[i][j][r] + xnv[j], 0.0f);
                    unsigned long long key =
                        ((unsigned long long)__float_as_uint(sc) << 32) | (unsigned int)t_;
                    best = (key < best) ? key : best;
                }
            }
            #pragma unroll
            for (int sft = 1; sft < 16; sft <<= 1) {
                unsigned long long o = __shfl_xor(best, sft);
                best = (o < best) ? o : best;
            }
            if (lrow == 0) atomicMin(&skey[lm], best);   // LDS atomic (fast)
        }
    }
    __syncthreads();
    if (tid < 128)
        tilekey[(size_t)n_t * Mp + mtile + tid] = skey[tid];
}

// One block per query: tile-key min -> M; qualifying tiles -> bf16 row rescore
// -> candidate rows -> exact fp32 rescore -> argmin -> classify.
__global__ __launch_bounds__(256) void finish(
    const unsigned long long* __restrict__ tilekey,   // [ntiles][Mp]
    const unsigned short* __restrict__ Bh, const float* __restrict__ xn2,
    const float* __restrict__ xqf, const float* __restrict__ q2,
    const float* __restrict__ X,
    const int* __restrict__ labels, const int* __restrict__ nbr,
    const int* __restrict__ cali, float* __restrict__ out,
    int ntiles, int Mp, int knm1, int nb_cali, int nb_train, int B)
{
    __shared__ float sxq[256];
    __shared__ unsigned long long wmin[4];
    __shared__ unsigned long long Mshare;
    __shared__ int tlist[TCAP];
    __shared__ int tcnt;
    __shared__ unsigned int cand[CCAP];
    __shared__ int ccnt;
    __shared__ unsigned long long wbest[4];
    __shared__ int sclosest;

    const int q = blockIdx.x;
    const int tid = threadIdx.x;
    const int wave = tid >> 6;
    const int lane = tid & 63;

    if (tid == 0) { tcnt = 0; ccnt = 0; }
    sxq[tid] = xqf[(size_t)q * 256 + tid];
    const float q2v = q2[q];

    // ---- min over tile keys ----
    unsigned long long bk = ~0ULL;
    for (int i = tid; i < ntiles; i += 256) {
        unsigned long long k = tilekey[(size_t)i * Mp + q];
        bk = (k < bk) ? k : bk;
    }
    #pragma unroll
    for (int s = 1; s < 64; s <<= 1) {
        unsigned long long o = __shfl_xor(bk, s);
        bk = (o < bk) ? o : bk;
    }
    if (lane == 0) wmin[wave] = bk;
    __syncthreads();
    if (tid == 0) {
        unsigned long long m = wmin[0];
        m = (wmin[1] < m) ? wmin[1] : m;
        m = (wmin[2] < m) ? wmin[2] : m;
        m = (wmin[3] < m) ? wmin[3] : m;
        Mshare = m;
    }
    __syncthreads();
    const float thr = __uint_as_float((unsigned)(Mshare >> 32)) + WND;

    // ---- qualifying tiles ----
    for (int i = tid; i < ntiles; i += 256) {
        float sc = __uint_as_float((unsigned)(tilekey[(size_t)i * Mp + q] >> 32));
        if (sc <= thr) {
            int p = atomicAdd(&tcnt, 1);
            if (p < TCAP) tlist[p] = i;
        }
    }
    __syncthreads();
    int ntl = tcnt; if (ntl > TCAP) ntl = TCAP;

    // ---- bf16 row rescore of qualifying tiles (fp32 VALU, same error bound) ----
    const int r2 = tid >> 1, half = tid & 1;
    for (int li = 0; li < ntl; ++li) {
        int t = tlist[li] * 128 + r2;
        const ushort8* bp = (const ushort8*)(Bh + (size_t)t * 256 + half * 128);
        float dot = 0.f;
        #pragma unroll
        for (int k = 0; k < 16; ++k) {
            ushort8 bv = bp[k];
            #pragma unroll
            for (int e = 0; e < 8; ++e) {
                float bf = __uint_as_float((unsigned)bv[e] << 16);
                dot += sxq[half * 128 + k * 8 + e] * bf;
            }
        }
        dot += __shfl_xor(dot, 1);
        if (half == 0) {
            float sc = q2v - 2.0f * dot + xn2[t];   // pads: xn2=3e38 -> excluded
            if (sc <= thr) {
                int p = atomicAdd(&ccnt, 1);
                if (p < CCAP) cand[p] = (unsigned)t;
            }
        }
    }
    __syncthreads();
    int nc = ccnt; if (nc > CCAP) nc = CCAP;

    // ---- exact fp32 rescore of candidate rows ----
    unsigned long long best = ~0ULL;
    const float4 qa = ((const float4*)sxq)[lane];
    for (int c = wave; c < nc; c += 4) {
        int t = (int)cand[c];
        float4 b = ((const float4*)(X + (size_t)t * 256))[lane];
        float dot = qa.x * b.x + qa.y * b.y + qa.z * b.z + qa.w * b.w;
        #pragma unroll
        for (int s = 1; s < 64; s <<= 1) dot += __shfl_xor(dot, s);
        float sc = fmaxf(q2v - 2.0f * dot + xn2[t], 0.0f);
        unsigned long long key =
            ((unsigned long long)__float_as_uint(sc) << 32) | (unsigned)t;
        best = (key < best) ? key : best;
    }
    if (lane == 0) wbest[wave] = best;
    __syncthreads();
    if (tid == 0) {
        unsigned long long b = wbest[0];
        b = (wbest[1] < b) ? wbest[1] : b;
        b = (wbest[2] < b) ? wbest[2] : b;
        b = (wbest[3] < b) ? wbest[3] : b;
        sclosest = (int)(b & 0xFFFFFFFFULL);
    }
    __syncthreads();

    // ---- classify (wave 0 only) ----
    if (wave == 0) {
        const int closest = sclosest;
        const int K = knm1 + 1;   // 75
        int lbl0 = -1, lbl1 = -1;
        if (lane < K) {
            int idx = (lane == 0) ? closest : nbr[(size_t)closest * knm1 + (lane - 1)];
            lbl0 = labels[idx];
        }
        int j2 = lane + 64;
        if (j2 < K) {
            int idx = nbr[(size_t)closest * knm1 + (j2 - 1)];
            lbl1 = labels[idx];
        }
        int bestc = 0, bestp = -1;
        #pragma unroll
        for (int c = 0; c < 10; ++c) {
            int cn = __popcll(__ballot(lbl0 == c)) + __popcll(__ballot(lbl1 == c));
            int v = K - cn;
            int lo = 0, hi = nb_cali;
            while (lo < hi) {                 // bisect_left
                int mid = (lo + hi) >> 1;
                if (cali[mid] < v) lo = mid + 1; else hi = mid;
            }
            int p = nb_cali - lo;
            if (p > bestp) { bestp = p; bestc = c; }   // strict > == first-occurrence
        }
        float pv = (float)bestp / (float)nb_cali;
        if (lane < 10)
            out[(size_t)q * 10 + lane] = (lane == bestc) ? pv : 0.0f;
    }
}

extern "C" void kernel_launch(void* const* d_in, const int* in_sizes, int n_in,
                              void* d_out, int out_size, void* d_ws, size_t ws_size,
                              hipStream_t stream) {
    const float* x      = (const float*)d_in[0];
    const float* X      = (const float*)d_in[1];
    const float* center = (const float*)d_in[2];
    const int* labels   = (const int*)d_in[3];
    const int* nbr      = (const int*)d_in[4];
    const int* cali     = (const int*)d_in[5];
    float* out = (float*)d_out;

    const int d        = in_sizes[2];              // 256
    const int B        = in_sizes[0] / d;          // 1024
    const int nb_train = in_sizes[3];              // 100000
    const int knm1     = in_sizes[4] / nb_train;   // 74
    const int nb_cali  = in_sizes[5];              // 1000

    const int Mp = (B + 127) & ~127;               // 1024
    const int Np = (nb_train + 127) & ~127;        // 100096
    const int ntiles = Np / 128;                   // 782
    const int mtiles = Mp / 128;                   // 8
    const int nper   = (ntiles + 7) / 8;           // 98

    char* ws = (char*)d_ws;
    size_t off = 0;
    unsigned long long* tilekey = (unsigned long long*)(ws + off);
    off += (size_t)ntiles * Mp * 8;
    float* q2   = (float*)(ws + off); off += (size_t)Mp * 4;
    float* xqf  = (float*)(ws + off); off += (size_t)Mp * 256 * 4;
    float* xn2  = (float*)(ws + off); off += (size_t)Np * 4;
    unsigned short* Ah = (unsigned short*)(ws + off); off += (size_t)Mp * 256 * 2;
    unsigned short* Bh = (unsigned short*)(ws + off); off += (size_t)Np * 256 * 2;

    prep_all<<<Np / 4 + Mp, 256, 0, stream>>>(X, x, center, Bh, xn2,
                                              Ah, xqf, q2,
                                              nb_train, Np, B, Mp);
    mfma_min<<<8 * nper * mtiles, 256, 0, stream>>>(
        Ah, Bh, q2, xn2, tilekey, nb_train, B, Mp, ntiles, nper, mtiles);
    finish<<<B, 256, 0, stream>>>(tilekey, Bh, xn2, xqf, q2, X,
                                  labels, nbr, cali, out,
                                  ntiles, Mp, knm1, nb_cali, nb_train, B);
}

// Round 8
// 416.405 us; speedup vs baseline: 1.7254x; 1.0046x over previous
//
#include <hip/hip_runtime.h>
#include <stdint.h>

// ---------------------------------------------------------------------------
// DkNN round 8: round-7 pipeline with tilekey transposed to [q][tile].
//  - mfma_min epilogue: scattered 8-B stores (stride ntiles*8); all writers of
//    a 64-B line are same-XCD (swizzle) -> merged in XCD L2, ~6.4 MB net.
//  - finish: per-query tile-key row is contiguous (6.3 KB) -> coalesced scan.
//  Error bound unchanged: bf16 rel err <= 2^-8/operand -> |d2~ - d2| < 0.019,
//  window 0.04 > 2*0.019, so the true argmin always survives both filters.
// ---------------------------------------------------------------------------

typedef __attribute__((ext_vector_type(8))) short short8;   // 8 bf16 = 4 VGPR
typedef __attribute__((ext_vector_type(8))) unsigned short ushort8;
typedef __attribute__((ext_vector_type(4))) float float4v;  // MFMA C/D

#define WND 0.04f
#define TCAP 32
#define CCAP 32

static __device__ __forceinline__ unsigned short bf16_rn(float f) {
    unsigned int u = __float_as_uint(f);
    unsigned int r = (u + 0x7FFFu + ((u >> 16) & 1u)) >> 16;
    return (unsigned short)r;
}

static __device__ __forceinline__ void gload_lds16(const void* g, void* l) {
    __builtin_amdgcn_global_load_lds(
        (const __attribute__((address_space(1))) unsigned int*)g,
        (__attribute__((address_space(3))) unsigned int*)l, 16, 0, 0);
}

// Fused prep: blocks [0, Np/4) convert train rows; blocks [Np/4, Np/4+Mp)
// prep one query row each.
__global__ void prep_all(const float* __restrict__ X, const float* __restrict__ x,
                         const float* __restrict__ center,
                         unsigned short* __restrict__ Bh, float* __restrict__ xn2,
                         unsigned short* __restrict__ Ah, float* __restrict__ xqf,
                         float* __restrict__ q2,
                         int nb_train, int Np, int B, int Mp) {
    const int tid = threadIdx.x;
    const int tb = Np >> 2;
    if (blockIdx.x < (unsigned)tb) {
        int row = blockIdx.x * 4 + (tid >> 6);
        int lane = tid & 63;
        if (row >= nb_train) {
            *(ushort4*)(Bh + (size_t)row * 256 + lane * 4) = make_ushort4(0, 0, 0, 0);
            if (lane == 0) xn2[row] = 3.0e38f;
            return;
        }
        float4 v = ((const float4*)(X + (size_t)row * 256))[lane];
        ushort4 h;
        h.x = bf16_rn(v.x); h.y = bf16_rn(v.y);
        h.z = bf16_rn(v.z); h.w = bf16_rn(v.w);
        *(ushort4*)(Bh + (size_t)row * 256 + lane * 4) = h;
        float ss = v.x * v.x + v.y * v.y + v.z * v.z + v.w * v.w;
        #pragma unroll
        for (int s = 1; s < 64; s <<= 1) ss += __shfl_xor(ss, s);
        if (lane == 0) xn2[row] = ss;
        return;
    }
    int row = blockIdx.x - tb;
    if (row >= Mp) return;
    if (row >= B) {
        Ah[(size_t)row * 256 + tid] = 0;
        if (tid == 0) q2[row] = 0.0f;
        return;
    }
    float v = x[(size_t)row * 256 + tid];
    float ss = v * v;
    #pragma unroll
    for (int s = 1; s < 64; s <<= 1) ss += __shfl_xor(ss, s);
    __shared__ float partial[4];
    __shared__ float partial2[4];
    if ((tid & 63) == 0) partial[tid >> 6] = ss;
    __syncthreads();
    float tot = partial[0] + partial[1] + partial[2] + partial[3];
    float inv = 1.0f / sqrtf(tot);
    float val = v * inv - center[tid];
    Ah[(size_t)row * 256 + tid] = bf16_rn(val);
    xqf[(size_t)row * 256 + tid] = val;
    float ss2 = val * val;
    #pragma unroll
    for (int s = 1; s < 64; s <<= 1) ss2 += __shfl_xor(ss2, s);
    if ((tid & 63) == 0) partial2[tid >> 6] = ss2;
    __syncthreads();
    if (tid == 0) q2[row] = partial2[0] + partial2[1] + partial2[2] + partial2[3];
}

// 128x128 tile, 4 waves x 64x64 quadrants, K=256 in 4 steps of BK=64.
// XCD-swizzled 1D grid. Epilogue: per-(q,tile) packed min -> tilekey[q][n_t]
// (scattered 8-B stores, same-XCD line writers -> L2 merge; no atomics).
__global__ __launch_bounds__(256, 4) void mfma_min(
    const unsigned short* __restrict__ Ah,  // Mp x 256 bf16
    const unsigned short* __restrict__ Bh,  // Np x 256 bf16
    const float* __restrict__ q2, const float* __restrict__ xn2,
    unsigned long long* __restrict__ tilekey,   // [Mp][ntiles]
    int nb_train, int B, int Mp, int ntiles, int nper, int mtiles)
{
    __shared__ unsigned short As[128 * 64];   // [row][chunk ^ (row&7)] 16B chunks
    __shared__ unsigned short Bs[128 * 64];
    __shared__ unsigned long long skey[128];

    const int bid = blockIdx.x;
    const int xcd = bid & 7;
    const int s_  = bid >> 3;
    const int n_t = xcd * nper + (s_ / mtiles);
    const int m_t = s_ - (s_ / mtiles) * mtiles;
    if (n_t >= ntiles) return;
    const int mtile = m_t * 128;
    const int ntile = n_t * 128;

    const int tid  = threadIdx.x;
    const int wave = tid >> 6;
    const int lane = tid & 63;

    if (tid < 128) skey[tid] = ~0ULL;

    // staging role: waves 0,1 stage A rows [0:64),[64:128); waves 2,3 for B
    const int isB   = wave >> 1;
    const int Rwave = (wave & 1) * 64;
    const int lrow8  = lane >> 3;
    const int lchunk = lane & 7;
    const unsigned short* sbase = isB
        ? (Bh + (size_t)(ntile + Rwave + lrow8) * 256 + (size_t)((lchunk ^ lrow8) * 8))
        : (Ah + (size_t)(mtile + Rwave + lrow8) * 256 + (size_t)((lchunk ^ lrow8) * 8));
    unsigned short* lwave = (isB ? Bs : As) + Rwave * 64;

    // compute role: quadrant
    const int mq = (wave >> 1) * 64;
    const int nq = (wave & 1) * 64;
    const int lrow = lane & 15;
    const int kseg = lane >> 4;
    const int sw = lrow & 7;

    float4v acc[4][4];
    #pragma unroll
    for (int i = 0; i < 4; ++i)
        #pragma unroll
        for (int j = 0; j < 4; ++j)
            acc[i][j] = (float4v){0.f, 0.f, 0.f, 0.f};

    for (int s = 0; s < 4; ++s) {
        const unsigned short* g = sbase + s * 64;
        __syncthreads();
        #pragma unroll
        for (int q = 0; q < 8; ++q)
            gload_lds16(g + q * 2048, lwave + q * 512);
        __syncthreads();
        #pragma unroll
        for (int t = 0; t < 2; ++t) {
            const int wch = ((t * 4 + kseg) ^ sw) * 8;
            short8 a[4], b[4];
            #pragma unroll
            for (int i = 0; i < 4; ++i)
                a[i] = *(const short8*)&As[(mq + i * 16 + lrow) * 64 + wch];
            #pragma unroll
            for (int j = 0; j < 4; ++j)
                b[j] = *(const short8*)&Bs[(nq + j * 16 + lrow) * 64 + wch];
            #pragma unroll
            for (int i = 0; i < 4; ++i)
                #pragma unroll
                for (int j = 0; j < 4; ++j)
                    acc[i][j] = __builtin_amdgcn_mfma_f32_16x16x32_bf16(
                        a[i], b[j], acc[i][j], 0, 0, 0);
        }
    }

    float xnv[4];
    #pragma unroll
    for (int j = 0; j < 4; ++j)
        xnv[j] = xn2[ntile + nq + j * 16 + lrow];   // pads hold 3e38

    #pragma unroll
    for (int i = 0; i < 4; ++i) {
        #pragma unroll
        for (int r = 0; r < 4; ++r) {
            const int lm = mq + i * 16 + kseg * 4 + r;
            const int mi = mtile + lm;
            unsigned long long best = ~0ULL;
            if (mi < B) {
                float q2v = q2[mi];
                #pragma unroll
                for (int j = 0; j < 4; ++j) {
                    int t_ = ntile + nq + j * 16 + lrow;
                    float sc = fmaxf(q2v - 2.0f * acc[i][j][r] + xnv[j], 0.0f);
                    unsigned long long key =
                        ((unsigned long long)__float_as_uint(sc) << 32) | (unsigned int)t_;
                    best = (key < best) ? key : best;
                }
            }
            #pragma unroll
            for (int sft = 1; sft < 16; sft <<= 1) {
                unsigned long long o = __shfl_xor(best, sft);
                best = (o < best) ? o : best;
            }
            if (lrow == 0) atomicMin(&skey[lm], best);   // LDS atomic (fast)
        }
    }
    __syncthreads();
    if (tid < 128)
        tilekey[(size_t)(mtile + tid) * ntiles + n_t] = skey[tid];
}

// One block per query: contiguous tile-key row -> M; qualifying tiles -> bf16
// row rescore -> candidate rows -> exact fp32 rescore -> argmin -> classify.
__global__ __launch_bounds__(256) void finish(
    const unsigned long long* __restrict__ tilekey,   // [Mp][ntiles]
    const unsigned short* __restrict__ Bh, const float* __restrict__ xn2,
    const float* __restrict__ xqf, const float* __restrict__ q2,
    const float* __restrict__ X,
    const int* __restrict__ labels, const int* __restrict__ nbr,
    const int* __restrict__ cali, float* __restrict__ out,
    int ntiles, int Mp, int knm1, int nb_cali, int nb_train, int B)
{
    __shared__ float sxq[256];
    __shared__ unsigned long long wmin[4];
    __shared__ unsigned long long Mshare;
    __shared__ int tlist[TCAP];
    __shared__ int tcnt;
    __shared__ unsigned int cand[CCAP];
    __shared__ int ccnt;
    __shared__ unsigned long long wbest[4];
    __shared__ int sclosest;

    const int q = blockIdx.x;
    const int tid = threadIdx.x;
    const int wave = tid >> 6;
    const int lane = tid & 63;

    if (tid == 0) { tcnt = 0; ccnt = 0; }
    sxq[tid] = xqf[(size_t)q * 256 + tid];
    const float q2v = q2[q];
    const unsigned long long* tk = tilekey + (size_t)q * ntiles;

    // ---- min over tile keys (coalesced contiguous row) ----
    unsigned long long bk = ~0ULL;
    for (int i = tid; i < ntiles; i += 256) {
        unsigned long long k = tk[i];
        bk = (k < bk) ? k : bk;
    }
    #pragma unroll
    for (int s = 1; s < 64; s <<= 1) {
        unsigned long long o = __shfl_xor(bk, s);
        bk = (o < bk) ? o : bk;
    }
    if (lane == 0) wmin[wave] = bk;
    __syncthreads();
    if (tid == 0) {
        unsigned long long m = wmin[0];
        m = (wmin[1] < m) ? wmin[1] : m;
        m = (wmin[2] < m) ? wmin[2] : m;
        m = (wmin[3] < m) ? wmin[3] : m;
        Mshare = m;
    }
    __syncthreads();
    const float thr = __uint_as_float((unsigned)(Mshare >> 32)) + WND;

    // ---- qualifying tiles (row now L1/L2-hot) ----
    for (int i = tid; i < ntiles; i += 256) {
        float sc = __uint_as_float((unsigned)(tk[i] >> 32));
        if (sc <= thr) {
            int p = atomicAdd(&tcnt, 1);
            if (p < TCAP) tlist[p] = i;
        }
    }
    __syncthreads();
    int ntl = tcnt; if (ntl > TCAP) ntl = TCAP;

    // ---- bf16 row rescore of qualifying tiles (fp32 VALU, same error bound) ----
    const int r2 = tid >> 1, half = tid & 1;
    for (int li = 0; li < ntl; ++li) {
        int t = tlist[li] * 128 + r2;
        const ushort8* bp = (const ushort8*)(Bh + (size_t)t * 256 + half * 128);
        float dot = 0.f;
        #pragma unroll
        for (int k = 0; k < 16; ++k) {
            ushort8 bv = bp[k];
            #pragma unroll
            for (int e = 0; e < 8; ++e) {
                float bf = __uint_as_float((unsigned)bv[e] << 16);
                dot += sxq[half * 128 + k * 8 + e] * bf;
            }
        }
        dot += __shfl_xor(dot, 1);
        if (half == 0) {
            float sc = q2v - 2.0f * dot + xn2[t];   // pads: xn2=3e38 -> excluded
            if (sc <= thr) {
                int p = atomicAdd(&ccnt, 1);
                if (p < CCAP) cand[p] = (unsigned)t;
            }
        }
    }
    __syncthreads();
    int nc = ccnt; if (nc > CCAP) nc = CCAP;

    // ---- exact fp32 rescore of candidate rows ----
    unsigned long long best = ~0ULL;
    const float4 qa = ((const float4*)sxq)[lane];
    for (int c = wave; c < nc; c += 4) {
        int t = (int)cand[c];
        float4 b = ((const float4*)(X + (size_t)t * 256))[lane];
        float dot = qa.x * b.x + qa.y * b.y + qa.z * b.z + qa.w * b.w;
        #pragma unroll
        for (int s = 1; s < 64; s <<= 1) dot += __shfl_xor(dot, s);
        float sc = fmaxf(q2v - 2.0f * dot + xn2[t], 0.0f);
        unsigned long long key =
            ((unsigned long long)__float_as_uint(sc) << 32) | (unsigned)t;
        best = (key < best) ? key : best;
    }
    if (lane == 0) wbest[wave] = best;
    __syncthreads();
    if (tid == 0) {
        unsigned long long b = wbest[0];
        b = (wbest[1] < b) ? wbest[1] : b;
        b = (wbest[2] < b) ? wbest[2] : b;
        b = (wbest[3] < b) ? wbest[3] : b;
        sclosest = (int)(b & 0xFFFFFFFFULL);
    }
    __syncthreads();

    // ---- classify (wave 0 only) ----
    if (wave == 0) {
        const int closest = sclosest;
        const int K = knm1 + 1;   // 75
        int lbl0 = -1, lbl1 = -1;
        if (lane < K) {
            int idx = (lane == 0) ? closest : nbr[(size_t)closest * knm1 + (lane - 1)];
            lbl0 = labels[idx];
        }
        int j2 = lane + 64;
        if (j2 < K) {
            int idx = nbr[(size_t)closest * knm1 + (j2 - 1)];
            lbl1 = labels[idx];
        }
        int bestc = 0, bestp = -1;
        #pragma unroll
        for (int c = 0; c < 10; ++c) {
            int cn = __popcll(__ballot(lbl0 == c)) + __popcll(__ballot(lbl1 == c));
            int v = K - cn;
            int lo = 0, hi = nb_cali;
            while (lo < hi) {                 // bisect_left
                int mid = (lo + hi) >> 1;
                if (cali[mid] < v) lo = mid + 1; else hi = mid;
            }
            int p = nb_cali - lo;
            if (p > bestp) { bestp = p; bestc = c; }   // strict > == first-occurrence
        }
        float pv = (float)bestp / (float)nb_cali;
        if (lane < 10)
            out[(size_t)q * 10 + lane] = (lane == bestc) ? pv : 0.0f;
    }
}

extern "C" void kernel_launch(void* const* d_in, const int* in_sizes, int n_in,
                              void* d_out, int out_size, void* d_ws, size_t ws_size,
                              hipStream_t stream) {
    const float* x      = (const float*)d_in[0];
    const float* X      = (const float*)d_in[1];
    const float* center = (const float*)d_in[2];
    const int* labels   = (const int*)d_in[3];
    const int* nbr      = (const int*)d_in[4];
    const int* cali     = (const int*)d_in[5];
    float* out = (float*)d_out;

    const int d        = in_sizes[2];              // 256
    const int B        = in_sizes[0] / d;          // 1024
    const int nb_train = in_sizes[3];              // 100000
    const int knm1     = in_sizes[4] / nb_train;   // 74
    const int nb_cali  = in_sizes[5];              // 1000

    const int Mp = (B + 127) & ~127;               // 1024
    const int Np = (nb_train + 127) & ~127;        // 100096
    const int ntiles = Np / 128;                   // 782
    const int mtiles = Mp / 128;                   // 8
    const int nper   = (ntiles + 7) / 8;           // 98

    char* ws = (char*)d_ws;
    size_t off = 0;
    unsigned long long* tilekey = (unsigned long long*)(ws + off);
    off += (size_t)Mp * ntiles * 8;
    float* q2   = (float*)(ws + off); off += (size_t)Mp * 4;
    float* xqf  = (float*)(ws + off); off += (size_t)Mp * 256 * 4;
    float* xn2  = (float*)(ws + off); off += (size_t)Np * 4;
    unsigned short* Ah = (unsigned short*)(ws + off); off += (size_t)Mp * 256 * 2;
    unsigned short* Bh = (unsigned short*)(ws + off); off += (size_t)Np * 256 * 2;

    prep_all<<<Np / 4 + Mp, 256, 0, stream>>>(X, x, center, Bh, xn2,
                                              Ah, xqf, q2,
                                              nb_train, Np, B, Mp);
    mfma_min<<<8 * nper * mtiles, 256, 0, stream>>>(
        Ah, Bh, q2, xn2, tilekey, nb_train, B, Mp, ntiles, nper, mtiles);
    finish<<<B, 256, 0, stream>>>(tilekey, Bh, xn2, xqf, q2, X,
                                  labels, nbr, cali, out,
                                  ntiles, Mp, knm1, nb_cali, nb_train, B);
}

// Round 9
// 384.301 us; speedup vs baseline: 1.8696x; 1.0835x over previous
//
#include <hip/hip_runtime.h>
#include <stdint.h>

// ---------------------------------------------------------------------------
// DkNN round 9: GEMM emits per-(q,tile) min key + 128-bit candidate bitmask.
//  K1 prep_all:  train rows -> bf16 Bh + xn2 ; queries -> fp32 xqf + bf16 Ah + q2.
//  K2 mfma_min:  Ah*Bh bf16 MFMA GEMM (K=256), 128x128 tiles, XCD-swizzled.
//    Epilogue pass 1: per-(q,tile) min key (LDS atomicMin + 16-lane shuffle).
//    Epilogue pass 2: 128-bit mask of rows with sc <= tilemin + WND
//    (shuffle-OR; unique writer wave per (row,half) -> plain LDS stores).
//    Stores keys[q][tile] (8B) and masks[q][tile] (16B). No global atomics.
//  K3 finish:    scan contiguous key row -> M; qualifying tiles
//    (keyscore <= M+WND) -> decode mask bits -> exact fp32 rescore from X
//    (~3 rows/query) -> true argmin -> classify fused.
//  Bound: bf16 rel err <= 2^-8/operand -> |d2~-d2| <= 0.019; argmin's approx
//  score is within 0.038 of its tile-min and of M -> always in mask+window.
// ---------------------------------------------------------------------------

typedef __attribute__((ext_vector_type(8))) short short8;   // 8 bf16 = 4 VGPR
typedef __attribute__((ext_vector_type(4))) float float4v;  // MFMA C/D
typedef __attribute__((ext_vector_type(2))) unsigned long long ulong2v;

#define WND 0.04f
#define CCAP 64

static __device__ __forceinline__ unsigned short bf16_rn(float f) {
    unsigned int u = __float_as_uint(f);
    unsigned int r = (u + 0x7FFFu + ((u >> 16) & 1u)) >> 16;
    return (unsigned short)r;
}

static __device__ __forceinline__ void gload_lds16(const void* g, void* l) {
    __builtin_amdgcn_global_load_lds(
        (const __attribute__((address_space(1))) unsigned int*)g,
        (__attribute__((address_space(3))) unsigned int*)l, 16, 0, 0);
}

// Fused prep: blocks [0, Np/4) convert train rows; blocks [Np/4, Np/4+Mp)
// prep one query row each.
__global__ void prep_all(const float* __restrict__ X, const float* __restrict__ x,
                         const float* __restrict__ center,
                         unsigned short* __restrict__ Bh, float* __restrict__ xn2,
                         unsigned short* __restrict__ Ah, float* __restrict__ xqf,
                         float* __restrict__ q2,
                         int nb_train, int Np, int B, int Mp) {
    const int tid = threadIdx.x;
    const int tb = Np >> 2;
    if (blockIdx.x < (unsigned)tb) {
        int row = blockIdx.x * 4 + (tid >> 6);
        int lane = tid & 63;
        if (row >= nb_train) {
            *(ushort4*)(Bh + (size_t)row * 256 + lane * 4) = make_ushort4(0, 0, 0, 0);
            if (lane == 0) xn2[row] = 3.0e38f;
            return;
        }
        float4 v = ((const float4*)(X + (size_t)row * 256))[lane];
        ushort4 h;
        h.x = bf16_rn(v.x); h.y = bf16_rn(v.y);
        h.z = bf16_rn(v.z); h.w = bf16_rn(v.w);
        *(ushort4*)(Bh + (size_t)row * 256 + lane * 4) = h;
        float ss = v.x * v.x + v.y * v.y + v.z * v.z + v.w * v.w;
        #pragma unroll
        for (int s = 1; s < 64; s <<= 1) ss += __shfl_xor(ss, s);
        if (lane == 0) xn2[row] = ss;
        return;
    }
    int row = blockIdx.x - tb;
    if (row >= Mp) return;
    if (row >= B) {
        Ah[(size_t)row * 256 + tid] = 0;
        if (tid == 0) q2[row] = 0.0f;
        return;
    }
    float v = x[(size_t)row * 256 + tid];
    float ss = v * v;
    #pragma unroll
    for (int s = 1; s < 64; s <<= 1) ss += __shfl_xor(ss, s);
    __shared__ float partial[4];
    __shared__ float partial2[4];
    if ((tid & 63) == 0) partial[tid >> 6] = ss;
    __syncthreads();
    float tot = partial[0] + partial[1] + partial[2] + partial[3];
    float inv = 1.0f / sqrtf(tot);
    float val = v * inv - center[tid];
    Ah[(size_t)row * 256 + tid] = bf16_rn(val);
    xqf[(size_t)row * 256 + tid] = val;
    float ss2 = val * val;
    #pragma unroll
    for (int s = 1; s < 64; s <<= 1) ss2 += __shfl_xor(ss2, s);
    if ((tid & 63) == 0) partial2[tid >> 6] = ss2;
    __syncthreads();
    if (tid == 0) q2[row] = partial2[0] + partial2[1] + partial2[2] + partial2[3];
}

// 128x128 tile, 4 waves x 64x64 quadrants, K=256 in 4 steps of BK=64.
// XCD-swizzled 1D grid. Epilogue: min key + candidate bitmask per (q,tile).
__global__ __launch_bounds__(256, 4) void mfma_min(
    const unsigned short* __restrict__ Ah,  // Mp x 256 bf16
    const unsigned short* __restrict__ Bh,  // Np x 256 bf16
    const float* __restrict__ q2, const float* __restrict__ xn2,
    unsigned long long* __restrict__ keys,   // [Mp][ntiles]
    ulong2v* __restrict__ masks,             // [Mp][ntiles]
    int nb_train, int B, int Mp, int ntiles, int nper, int mtiles)
{
    __shared__ unsigned short As[128 * 64];   // [row][chunk ^ (row&7)] 16B chunks
    __shared__ unsigned short Bs[128 * 64];
    __shared__ unsigned long long skey[128];
    __shared__ unsigned long long smask[128][2];

    const int bid = blockIdx.x;
    const int xcd = bid & 7;
    const int s_  = bid >> 3;
    const int n_t = xcd * nper + (s_ / mtiles);
    const int m_t = s_ - (s_ / mtiles) * mtiles;
    if (n_t >= ntiles) return;
    const int mtile = m_t * 128;
    const int ntile = n_t * 128;

    const int tid  = threadIdx.x;
    const int wave = tid >> 6;
    const int lane = tid & 63;

    if (tid < 128) skey[tid] = ~0ULL;

    // staging role: waves 0,1 stage A rows [0:64),[64:128); waves 2,3 for B
    const int isB   = wave >> 1;
    const int Rwave = (wave & 1) * 64;
    const int lrow8  = lane >> 3;
    const int lchunk = lane & 7;
    const unsigned short* sbase = isB
        ? (Bh + (size_t)(ntile + Rwave + lrow8) * 256 + (size_t)((lchunk ^ lrow8) * 8))
        : (Ah + (size_t)(mtile + Rwave + lrow8) * 256 + (size_t)((lchunk ^ lrow8) * 8));
    unsigned short* lwave = (isB ? Bs : As) + Rwave * 64;

    // compute role: quadrant
    const int mq = (wave >> 1) * 64;
    const int nq = (wave & 1) * 64;
    const int lrow = lane & 15;
    const int kseg = lane >> 4;
    const int sw = lrow & 7;

    float4v acc[4][4];
    #pragma unroll
    for (int i = 0; i < 4; ++i)
        #pragma unroll
        for (int j = 0; j < 4; ++j)
            acc[i][j] = (float4v){0.f, 0.f, 0.f, 0.f};

    for (int s = 0; s < 4; ++s) {
        const unsigned short* g = sbase + s * 64;
        __syncthreads();
        #pragma unroll
        for (int q = 0; q < 8; ++q)
            gload_lds16(g + q * 2048, lwave + q * 512);
        __syncthreads();
        #pragma unroll
        for (int t = 0; t < 2; ++t) {
            const int wch = ((t * 4 + kseg) ^ sw) * 8;
            short8 a[4], b[4];
            #pragma unroll
            for (int i = 0; i < 4; ++i)
                a[i] = *(const short8*)&As[(mq + i * 16 + lrow) * 64 + wch];
            #pragma unroll
            for (int j = 0; j < 4; ++j)
                b[j] = *(const short8*)&Bs[(nq + j * 16 + lrow) * 64 + wch];
            #pragma unroll
            for (int i = 0; i < 4; ++i)
                #pragma unroll
                for (int j = 0; j < 4; ++j)
                    acc[i][j] = __builtin_amdgcn_mfma_f32_16x16x32_bf16(
                        a[i], b[j], acc[i][j], 0, 0, 0);
        }
    }

    float xnv[4];
    #pragma unroll
    for (int j = 0; j < 4; ++j)
        xnv[j] = xn2[ntile + nq + j * 16 + lrow];   // pads hold 3e38

    // ---- pass 1: per-(q,tile) min key ----
    #pragma unroll
    for (int i = 0; i < 4; ++i) {
        #pragma unroll
        for (int r = 0; r < 4; ++r) {
            const int lm = mq + i * 16 + kseg * 4 + r;
            const float q2v = q2[mtile + lm];
            unsigned long long best = ~0ULL;
            #pragma unroll
            for (int j = 0; j < 4; ++j) {
                int t_ = ntile + nq + j * 16 + lrow;
                float sc = fmaxf(q2v - 2.0f * acc[i][j][r] + xnv[j], 0.0f);
                unsigned long long key =
                    ((unsigned long long)__float_as_uint(sc) << 32) | (unsigned int)t_;
                best = (key < best) ? key : best;
            }
            #pragma unroll
            for (int sft = 1; sft < 16; sft <<= 1) {
                unsigned long long o = __shfl_xor(best, sft);
                best = (o < best) ? o : best;
            }
            if (lrow == 0) atomicMin(&skey[lm], best);   // LDS atomic (fast)
        }
    }
    __syncthreads();

    // ---- pass 2: candidate bitmask (rows with sc <= tilemin + WND) ----
    #pragma unroll
    for (int i = 0; i < 4; ++i) {
        #pragma unroll
        for (int r = 0; r < 4; ++r) {
            const int lm = mq + i * 16 + kseg * 4 + r;
            const float thr = __uint_as_float((unsigned)(skey[lm] >> 32)) + WND;
            const float q2v = q2[mtile + lm];
            unsigned long long mbits = 0;
            #pragma unroll
            for (int j = 0; j < 4; ++j) {
                float sc = fmaxf(q2v - 2.0f * acc[i][j][r] + xnv[j], 0.0f);
                if (sc <= thr) mbits |= 1ULL << (j * 16 + lrow);
            }
            #pragma unroll
            for (int sft = 1; sft < 16; sft <<= 1)
                mbits |= __shfl_xor(mbits, sft);
            if (lrow == 0) smask[lm][nq >> 6] = mbits;   // unique writer
        }
    }
    __syncthreads();
    if (tid < 128) {
        size_t idx = (size_t)(mtile + tid) * ntiles + n_t;
        keys[idx] = skey[tid];
        ulong2v m;
        m[0] = smask[tid][0];
        m[1] = smask[tid][1];
        masks[idx] = m;
    }
}

// One block per query: contiguous key row -> M; qualifying tiles -> mask
// decode -> exact fp32 rescore from X -> true argmin -> classify.
__global__ __launch_bounds__(256) void finish(
    const unsigned long long* __restrict__ keys,   // [Mp][ntiles]
    const ulong2v* __restrict__ masks,             // [Mp][ntiles]
    const float* __restrict__ xqf, const float* __restrict__ q2,
    const float* __restrict__ X, const float* __restrict__ xn2,
    const int* __restrict__ labels, const int* __restrict__ nbr,
    const int* __restrict__ cali, float* __restrict__ out,
    int ntiles, int knm1, int nb_cali, int nb_train, int B)
{
    __shared__ float sxq[256];
    __shared__ unsigned long long wmin[4];
    __shared__ unsigned long long Mshare;
    __shared__ unsigned int cand[CCAP];
    __shared__ int ccnt;
    __shared__ unsigned long long wbest[4];
    __shared__ int sclosest;

    const int q = blockIdx.x;
    const int tid = threadIdx.x;
    const int wave = tid >> 6;
    const int lane = tid & 63;

    if (tid == 0) ccnt = 0;
    sxq[tid] = xqf[(size_t)q * 256 + tid];
    const float q2v = q2[q];
    const unsigned long long* tk = keys + (size_t)q * ntiles;
    const ulong2v* tmk = masks + (size_t)q * ntiles;

    // ---- min over tile keys (coalesced contiguous row) ----
    unsigned long long bk = ~0ULL;
    for (int i = tid; i < ntiles; i += 256) {
        unsigned long long k = tk[i];
        bk = (k < bk) ? k : bk;
    }
    #pragma unroll
    for (int s = 1; s < 64; s <<= 1) {
        unsigned long long o = __shfl_xor(bk, s);
        bk = (o < bk) ? o : bk;
    }
    if (lane == 0) wmin[wave] = bk;
    __syncthreads();
    if (tid == 0) {
        unsigned long long m = wmin[0];
        m = (wmin[1] < m) ? wmin[1] : m;
        m = (wmin[2] < m) ? wmin[2] : m;
        m = (wmin[3] < m) ? wmin[3] : m;
        Mshare = m;
    }
    __syncthreads();
    const float thr = __uint_as_float((unsigned)(Mshare >> 32)) + WND;

    // ---- qualifying tiles: decode masks into candidate rows (L2-hot keys) ----
    for (int i = tid; i < ntiles; i += 256) {
        float sc = __uint_as_float((unsigned)(tk[i] >> 32));
        if (sc <= thr) {
            ulong2v m = tmk[i];
            unsigned long long lo = m[0], hi = m[1];
            while (lo) {
                int b = __builtin_ctzll(lo); lo &= lo - 1;
                int p = atomicAdd(&ccnt, 1);
                if (p < CCAP) cand[p] = (unsigned)(i * 128 + b);
            }
            while (hi) {
                int b = __builtin_ctzll(hi); hi &= hi - 1;
                int p = atomicAdd(&ccnt, 1);
                if (p < CCAP) cand[p] = (unsigned)(i * 128 + 64 + b);
            }
        }
    }
    __syncthreads();
    int nc = ccnt; if (nc > CCAP) nc = CCAP;

    // ---- exact fp32 rescore of candidate rows (one wave per row) ----
    unsigned long long best = ~0ULL;
    const float4 qa = ((const float4*)sxq)[lane];
    for (int c = wave; c < nc; c += 4) {
        int t = (int)cand[c];
        if (t >= nb_train) continue;   // pad rows can't appear (xn2=3e38) but guard
        float4 b = ((const float4*)(X + (size_t)t * 256))[lane];
        float dot = qa.x * b.x + qa.y * b.y + qa.z * b.z + qa.w * b.w;
        #pragma unroll
        for (int s = 1; s < 64; s <<= 1) dot += __shfl_xor(dot, s);
        float sc = fmaxf(q2v - 2.0f * dot + xn2[t], 0.0f);
        unsigned long long key =
            ((unsigned long long)__float_as_uint(sc) << 32) | (unsigned)t;
        best = (key < best) ? key : best;
    }
    if (lane == 0) wbest[wave] = best;
    __syncthreads();
    if (tid == 0) {
        unsigned long long b = wbest[0];
        b = (wbest[1] < b) ? wbest[1] : b;
        b = (wbest[2] < b) ? wbest[2] : b;
        b = (wbest[3] < b) ? wbest[3] : b;
        sclosest = (int)(b & 0xFFFFFFFFULL);
    }
    __syncthreads();

    // ---- classify (wave 0 only) ----
    if (wave == 0) {
        const int closest = sclosest;
        const int K = knm1 + 1;   // 75
        int lbl0 = -1, lbl1 = -1;
        if (lane < K) {
            int idx = (lane == 0) ? closest : nbr[(size_t)closest * knm1 + (lane - 1)];
            lbl0 = labels[idx];
        }
        int j2 = lane + 64;
        if (j2 < K) {
            int idx = nbr[(size_t)closest * knm1 + (j2 - 1)];
            lbl1 = labels[idx];
        }
        int bestc = 0, bestp = -1;
        #pragma unroll
        for (int c = 0; c < 10; ++c) {
            int cn = __popcll(__ballot(lbl0 == c)) + __popcll(__ballot(lbl1 == c));
            int v = K - cn;
            int lo = 0, hi = nb_cali;
            while (lo < hi) {                 // bisect_left
                int mid = (lo + hi) >> 1;
                if (cali[mid] < v) lo = mid + 1; else hi = mid;
            }
            int p = nb_cali - lo;
            if (p > bestp) { bestp = p; bestc = c; }   // strict > == first-occurrence
        }
        float pv = (float)bestp / (float)nb_cali;
        if (lane < 10)
            out[(size_t)q * 10 + lane] = (lane == bestc) ? pv : 0.0f;
    }
}

extern "C" void kernel_launch(void* const* d_in, const int* in_sizes, int n_in,
                              void* d_out, int out_size, void* d_ws, size_t ws_size,
                              hipStream_t stream) {
    const float* x      = (const float*)d_in[0];
    const float* X      = (const float*)d_in[1];
    const float* center = (const float*)d_in[2];
    const int* labels   = (const int*)d_in[3];
    const int* nbr      = (const int*)d_in[4];
    const int* cali     = (const int*)d_in[5];
    float* out = (float*)d_out;

    const int d        = in_sizes[2];              // 256
    const int B        = in_sizes[0] / d;          // 1024
    const int nb_train = in_sizes[3];              // 100000
    const int knm1     = in_sizes[4] / nb_train;   // 74
    const int nb_cali  = in_sizes[5];              // 1000

    const int Mp = (B + 127) & ~127;               // 1024
    const int Np = (nb_train + 127) & ~127;        // 100096
    const int ntiles = Np / 128;                   // 782
    const int mtiles = Mp / 128;                   // 8
    const int nper   = (ntiles + 7) / 8;           // 98

    char* ws = (char*)d_ws;
    size_t off = 0;
    unsigned long long* keys = (unsigned long long*)(ws + off);
    off += (size_t)Mp * ntiles * 8;
    ulong2v* masks = (ulong2v*)(ws + off);
    off += (size_t)Mp * ntiles * 16;
    float* q2   = (float*)(ws + off); off += (size_t)Mp * 4;
    float* xqf  = (float*)(ws + off); off += (size_t)Mp * 256 * 4;
    float* xn2  = (float*)(ws + off); off += (size_t)Np * 4;
    unsigned short* Ah = (unsigned short*)(ws + off); off += (size_t)Mp * 256 * 2;
    unsigned short* Bh = (unsigned short*)(ws + off); off += (size_t)Np * 256 * 2;

    prep_all<<<Np / 4 + Mp, 256, 0, stream>>>(X, x, center, Bh, xn2,
                                              Ah, xqf, q2,
                                              nb_train, Np, B, Mp);
    mfma_min<<<8 * nper * mtiles, 256, 0, stream>>>(
        Ah, Bh, q2, xn2, keys, masks, nb_train, B, Mp, ntiles, nper, mtiles);
    finish<<<B, 256, 0, stream>>>(keys, masks, xqf, q2, X, xn2,
                                  labels, nbr, cali, out,
                                  ntiles, knm1, nb_cali, nb_train, B);
}